// Round 1
// baseline (1943.814 us; speedup 1.0000x reference)
//
#include <hip/hip_runtime.h>
#include <hip/hip_bf16.h>

#define THREADS 256

// ---------------- degree / norm kernels ----------------

__global__ void k_deg_init(float* deg, int n) {
    int i = blockIdx.x * THREADS + threadIdx.x;
    if (i < n) deg[i] = 1.0f;  // self-loop contributes 1 to in-degree
}

__global__ void k_deg_hist(const int* __restrict__ dst, float* deg, int E) {
    int e = blockIdx.x * THREADS + threadIdx.x;
    if (e < E) unsafeAtomicAdd(&deg[dst[e]], 1.0f);
}

__global__ void k_dinv(float* deg, int n) {  // in-place deg -> rsqrt(deg)
    int i = blockIdx.x * THREADS + threadIdx.x;
    if (i < n) deg[i] = rsqrtf(fmaxf(deg[i], 1e-12f));
}

__global__ void k_edge_norm(const int* __restrict__ src, const int* __restrict__ dst,
                            const float* __restrict__ dinv, float* __restrict__ w, int E) {
    int e = blockIdx.x * THREADS + threadIdx.x;
    if (e < E) w[e] = dinv[src[e]] * dinv[dst[e]];
}

// ---------------- GEMM: C[M x N] = A[M x 128] @ W[128 x N], BN=64 tiles ----------------
// RELU_A applies max(0, .) to A on load (fuses layer-1 activation into GEMM2).

template <bool RELU_A>
__global__ __launch_bounds__(256) void k_gemm(const float* __restrict__ A,
                                              const float* __restrict__ W,
                                              float* __restrict__ C, int M, int N) {
    __shared__ float As[32][68];   // As[k][m], pad 4 keeps 16B alignment, tames conflicts
    __shared__ float Ws[32][68];   // Ws[k][n]
    const int t = threadIdx.x;
    const int m0 = blockIdx.x * 64;
    const int bn0 = blockIdx.y * 64;
    const int tm = t & 15;         // row group
    const int tn = t >> 4;         // col group
    float acc[4][4] = {};

    for (int kk = 0; kk < 128; kk += 32) {
        {   // A tile 64x32 -> transposed
            int r = t >> 3;            // 0..31
            int c = (t & 7) * 4;       // 0,4,..,28
#pragma unroll
            for (int i2 = 0; i2 < 2; ++i2) {
                int row = m0 + r + 32 * i2;
                float4 v = make_float4(0.f, 0.f, 0.f, 0.f);
                if (row < M) v = *(const float4*)(A + (size_t)row * 128 + kk + c);
                if (RELU_A) {
                    v.x = fmaxf(v.x, 0.f); v.y = fmaxf(v.y, 0.f);
                    v.z = fmaxf(v.z, 0.f); v.w = fmaxf(v.w, 0.f);
                }
                As[c + 0][r + 32 * i2] = v.x;
                As[c + 1][r + 32 * i2] = v.y;
                As[c + 2][r + 32 * i2] = v.z;
                As[c + 3][r + 32 * i2] = v.w;
            }
        }
        {   // W tile 32x64
            int r = t >> 4;            // 0..15
            int c = (t & 15) * 4;      // 0..60
#pragma unroll
            for (int i2 = 0; i2 < 2; ++i2) {
                int row = kk + r + 16 * i2;
                *(float4*)&Ws[r + 16 * i2][c] = *(const float4*)(W + (size_t)row * N + bn0 + c);
            }
        }
        __syncthreads();
#pragma unroll
        for (int k = 0; k < 32; ++k) {
            float4 a4 = *(const float4*)&As[k][4 * tm];
            float4 w4 = *(const float4*)&Ws[k][4 * tn];
            float av[4] = {a4.x, a4.y, a4.z, a4.w};
            float wv[4] = {w4.x, w4.y, w4.z, w4.w};
#pragma unroll
            for (int i = 0; i < 4; ++i)
#pragma unroll
                for (int j = 0; j < 4; ++j) acc[i][j] += av[i] * wv[j];
        }
        __syncthreads();
    }
#pragma unroll
    for (int i = 0; i < 4; ++i) {
        int row = m0 + 4 * tm + i;
        if (row < M) {
            float4 v = make_float4(acc[i][0], acc[i][1], acc[i][2], acc[i][3]);
            *(float4*)(C + (size_t)row * N + bn0 + 4 * tn) = v;
        }
    }
}

// ---------------- aggregation init: out = dinv[i]^2 * h + bias ----------------

__global__ void k_selfinit128(const float* __restrict__ h, const float* __restrict__ dinv,
                              const float* __restrict__ bias, float* __restrict__ out, int n) {
    int p = blockIdx.x * THREADS + threadIdx.x;  // float4 index
    if (p >= n * 32) return;
    int i = p >> 5, f4 = p & 31;
    float d = dinv[i];
    float d2 = d * d;
    float4 hv = ((const float4*)h)[p];
    float4 bv = ((const float4*)bias)[f4];
    float4 o = make_float4(d2 * hv.x + bv.x, d2 * hv.y + bv.y,
                           d2 * hv.z + bv.z, d2 * hv.w + bv.w);
    ((float4*)out)[p] = o;
}

__global__ void k_selfinit64(const float* __restrict__ h, const float* __restrict__ dinv,
                             const float* __restrict__ bias, float* __restrict__ out, int n) {
    int p = blockIdx.x * THREADS + threadIdx.x;  // float4 index
    if (p >= n * 16) return;
    int i = p >> 4, f4 = p & 15;
    float d = dinv[i];
    float d2 = d * d;
    float4 hv = ((const float4*)h)[p];
    float4 bv = ((const float4*)bias)[f4];
    float4 o = make_float4(d2 * hv.x + bv.x, d2 * hv.y + bv.y,
                           d2 * hv.z + bv.z, d2 * hv.w + bv.w);
    ((float4*)out)[p] = o;
}

// ---------------- edge scatter (atomic): out[dst] += w * h[src] ----------------
// One wave (64 lanes) per edge; F=128 -> float2/lane, F=64 -> float/lane.

__global__ __launch_bounds__(256) void k_scatter128(const int* __restrict__ src,
                                                    const int* __restrict__ dst,
                                                    const float* __restrict__ w,
                                                    const float* __restrict__ h,
                                                    float* __restrict__ out, int E) {
    int e = blockIdx.x * 4 + (threadIdx.x >> 6);
    if (e >= E) return;
    int lane = threadIdx.x & 63;
    int s = src[e], d = dst[e];
    float we = w[e];
    float2 hv = *(const float2*)(h + (size_t)s * 128 + lane * 2);
    float* o = out + (size_t)d * 128 + lane * 2;
    unsafeAtomicAdd(o, hv.x * we);
    unsafeAtomicAdd(o + 1, hv.y * we);
}

__global__ __launch_bounds__(256) void k_scatter64(const int* __restrict__ src,
                                                   const int* __restrict__ dst,
                                                   const float* __restrict__ w,
                                                   const float* __restrict__ h,
                                                   float* __restrict__ out, int E) {
    int e = blockIdx.x * 4 + (threadIdx.x >> 6);
    if (e >= E) return;
    int lane = threadIdx.x & 63;
    int s = src[e], d = dst[e];
    float we = w[e];
    float hv = h[(size_t)s * 64 + lane];
    unsafeAtomicAdd(out + (size_t)d * 64 + lane, hv * we);
}

// ---------------- launch ----------------

extern "C" void kernel_launch(void* const* d_in, const int* in_sizes, int n_in,
                              void* d_out, int out_size, void* d_ws, size_t ws_size,
                              hipStream_t stream) {
    const float* x  = (const float*)d_in[0];
    const int*   ei = (const int*)d_in[1];
    const float* W1 = (const float*)d_in[2];
    const float* b1 = (const float*)d_in[3];
    const float* W2 = (const float*)d_in[4];
    const float* b2 = (const float*)d_in[5];
    float* out = (float*)d_out;

    const int N = in_sizes[0] / 128;
    const int E = in_sizes[1] / 2;
    const int* src = ei;
    const int* dst = ei + E;

    // workspace carve (256B aligned)
    char* ws = (char*)d_ws;
    size_t off = 0;
    auto carve = [&](size_t bytes) -> void* {
        void* p = ws + off;
        off = (off + bytes + 255) & ~(size_t)255;
        return p;
    };
    float* dinv  = (float*)carve((size_t)N * 4);        // deg, then rsqrt in place
    float* wnorm = (float*)carve((size_t)E * 4);        // per-edge norm
    float* h     = (float*)carve((size_t)N * 128 * 4);  // x@W1; later reused for h2
    float* hagg  = (float*)carve((size_t)N * 128 * 4);  // aggregated layer-1 (pre-relu)
    float* h2    = h;                                   // h dead after scatter1

    const int gN   = (N + THREADS - 1) / THREADS;
    const int gE   = (E + THREADS - 1) / THREADS;
    const int gE4  = (E + 3) / 4;
    const int gMm  = (N + 63) / 64;

    // degrees + norms
    k_deg_init<<<gN, THREADS, 0, stream>>>(dinv, N);
    k_deg_hist<<<gE, THREADS, 0, stream>>>(dst, dinv, E);
    k_dinv<<<gN, THREADS, 0, stream>>>(dinv, N);
    k_edge_norm<<<gE, THREADS, 0, stream>>>(src, dst, dinv, wnorm, E);

    // layer 1: h = x @ W1
    k_gemm<false><<<dim3(gMm, 2), THREADS, 0, stream>>>(x, W1, h, N, 128);
    // hagg = dinv^2 * h + b1  (self-loop + bias)
    k_selfinit128<<<(N * 32 + THREADS - 1) / THREADS, THREADS, 0, stream>>>(h, dinv, b1, hagg, N);
    // hagg += sum_e w_e * h[src_e]
    k_scatter128<<<gE4, THREADS, 0, stream>>>(src, dst, wnorm, h, hagg, E);

    // layer 2: h2 = relu(hagg) @ W2   (relu fused into A-load)
    k_gemm<true><<<dim3(gMm, 1), THREADS, 0, stream>>>(hagg, W2, h2, N, 64);
    // out = dinv^2 * h2 + b2
    k_selfinit64<<<(N * 16 + THREADS - 1) / THREADS, THREADS, 0, stream>>>(h2, dinv, b2, out, N);
    // out += sum_e w_e * h2[src_e]
    k_scatter64<<<gE4, THREADS, 0, stream>>>(src, dst, wnorm, h2, out, E);
}

// Round 2
// 514.859 us; speedup vs baseline: 3.7754x; 3.7754x over previous
//
#include <hip/hip_runtime.h>
#include <hip/hip_bf16.h>

#define THREADS 256

// ---------------- CSR build: histogram, dinv, scan, permute ----------------

__global__ void k_zero_i(int* p, int n) {
    int i = blockIdx.x * THREADS + threadIdx.x;
    if (i < n) p[i] = 0;
}

__global__ void k_hist(const int* __restrict__ dst, int* __restrict__ cnt, int E) {
    int e = blockIdx.x * THREADS + threadIdx.x;
    if (e < E) atomicAdd(&cnt[dst[e]], 1);
}

__global__ void k_dinv(const int* __restrict__ cnt, float* __restrict__ dinv, int n) {
    int i = blockIdx.x * THREADS + threadIdx.x;
    if (i < n) dinv[i] = rsqrtf((float)cnt[i] + 1.0f);  // +1 = self-loop; deg >= 1 always
}

// per-block scan of 1024 ints (4/thread), exclusive within block; bsum gets block total
__global__ __launch_bounds__(256) void k_scan1(const int* __restrict__ cnt, int* __restrict__ part,
                                               int* __restrict__ bsum, int n) {
    __shared__ int s[256];
    int t = threadIdx.x;
    int base = blockIdx.x * 1024 + t * 4;
    int4 v = make_int4(0, 0, 0, 0);
    if (base + 3 < n) v = *(const int4*)(cnt + base);
    else {
        if (base < n) v.x = cnt[base];
        if (base + 1 < n) v.y = cnt[base + 1];
        if (base + 2 < n) v.z = cnt[base + 2];
        if (base + 3 < n) v.w = cnt[base + 3];
    }
    int mysum = v.x + v.y + v.z + v.w;
    s[t] = mysum;
    __syncthreads();
    for (int off = 1; off < 256; off <<= 1) {
        int add = (t >= off) ? s[t - off] : 0;
        __syncthreads();
        s[t] += add;
        __syncthreads();
    }
    int excl = s[t] - mysum;
    if (base < n) part[base] = excl;
    if (base + 1 < n) part[base + 1] = excl + v.x;
    if (base + 2 < n) part[base + 2] = excl + v.x + v.y;
    if (base + 3 < n) part[base + 3] = excl + v.x + v.y + v.z;
    if (t == 255) bsum[blockIdx.x] = s[255];
}

// single-block exclusive scan of block sums (nblk <= 128)
__global__ void k_scan2(int* bsum, int nblk) {
    __shared__ int s[128];
    int t = threadIdx.x;
    int v = (t < nblk) ? bsum[t] : 0;
    s[t] = v;
    __syncthreads();
    for (int off = 1; off < 128; off <<= 1) {
        int add = (t >= off) ? s[t - off] : 0;
        __syncthreads();
        s[t] += add;
        __syncthreads();
    }
    if (t < nblk) bsum[t] = s[t] - v;  // exclusive
}

// rp (aliases part) += block offset; also seed cursor; rp[n] = E
__global__ void k_addoff(int* __restrict__ rp, const int* __restrict__ bsum,
                         int* __restrict__ cursor, int n, int E) {
    int i = blockIdx.x * THREADS + threadIdx.x;
    if (i < n) {
        int v = rp[i] + bsum[i >> 10];
        rp[i] = v;
        cursor[i] = v;
    } else if (i == n) {
        rp[n] = E;
    }
}

// place each edge into its dst bucket; pack (src, norm-weight) as int2
__global__ void k_permute(const int* __restrict__ src, const int* __restrict__ dst,
                          const float* __restrict__ dinv, int* __restrict__ cursor,
                          int2* __restrict__ eperm, int E) {
    int e = blockIdx.x * THREADS + threadIdx.x;
    if (e >= E) return;
    int s = src[e], d = dst[e];
    int pos = atomicAdd(&cursor[d], 1);
    float w = dinv[s] * dinv[d];
    eperm[pos] = make_int2(s, __float_as_int(w));
}

// ---------------- GEMM: C[M x N] = A[M x 128] @ W[128 x N], BN=64 tiles ----------------

template <bool RELU_A>
__global__ __launch_bounds__(256) void k_gemm(const float* __restrict__ A,
                                              const float* __restrict__ W,
                                              float* __restrict__ C, int M, int N) {
    __shared__ float As[32][68];
    __shared__ float Ws[32][68];
    const int t = threadIdx.x;
    const int m0 = blockIdx.x * 64;
    const int bn0 = blockIdx.y * 64;
    const int tm = t & 15;
    const int tn = t >> 4;
    float acc[4][4] = {};

    for (int kk = 0; kk < 128; kk += 32) {
        {
            int r = t >> 3;
            int c = (t & 7) * 4;
#pragma unroll
            for (int i2 = 0; i2 < 2; ++i2) {
                int row = m0 + r + 32 * i2;
                float4 v = make_float4(0.f, 0.f, 0.f, 0.f);
                if (row < M) v = *(const float4*)(A + (size_t)row * 128 + kk + c);
                if (RELU_A) {
                    v.x = fmaxf(v.x, 0.f); v.y = fmaxf(v.y, 0.f);
                    v.z = fmaxf(v.z, 0.f); v.w = fmaxf(v.w, 0.f);
                }
                As[c + 0][r + 32 * i2] = v.x;
                As[c + 1][r + 32 * i2] = v.y;
                As[c + 2][r + 32 * i2] = v.z;
                As[c + 3][r + 32 * i2] = v.w;
            }
        }
        {
            int r = t >> 4;
            int c = (t & 15) * 4;
#pragma unroll
            for (int i2 = 0; i2 < 2; ++i2) {
                int row = kk + r + 16 * i2;
                *(float4*)&Ws[r + 16 * i2][c] = *(const float4*)(W + (size_t)row * N + bn0 + c);
            }
        }
        __syncthreads();
#pragma unroll
        for (int k = 0; k < 32; ++k) {
            float4 a4 = *(const float4*)&As[k][4 * tm];
            float4 w4 = *(const float4*)&Ws[k][4 * tn];
            float av[4] = {a4.x, a4.y, a4.z, a4.w};
            float wv[4] = {w4.x, w4.y, w4.z, w4.w};
#pragma unroll
            for (int i = 0; i < 4; ++i)
#pragma unroll
                for (int j = 0; j < 4; ++j) acc[i][j] += av[i] * wv[j];
        }
        __syncthreads();
    }
#pragma unroll
    for (int i = 0; i < 4; ++i) {
        int row = m0 + 4 * tm + i;
        if (row < M) {
            float4 v = make_float4(acc[i][0], acc[i][1], acc[i][2], acc[i][3]);
            *(float4*)(C + (size_t)row * N + bn0 + 4 * tn) = v;
        }
    }
}

// ---------------- CSR gather: out[d] = d2*h[d] + b + sum_e w_e h[src_e] ----------------
// One wave per node. F=128: float2/lane; F=64: float/lane. No atomics.

__global__ __launch_bounds__(256) void k_gather128(const int* __restrict__ rp,
                                                   const int2* __restrict__ eperm,
                                                   const float* __restrict__ dinv,
                                                   const float* __restrict__ h,
                                                   const float* __restrict__ bias,
                                                   float* __restrict__ out, int n) {
    int node = blockIdx.x * 4 + (threadIdx.x >> 6);
    if (node >= n) return;
    int lane = threadIdx.x & 63;
    int beg = rp[node], end = rp[node + 1];
    float dv = dinv[node];
    float d2 = dv * dv;
    const float2* hp = (const float2*)h;  // row stride 64 float2
    float2 acc = hp[(size_t)node * 64 + lane];
    float2 bv = ((const float2*)bias)[lane];
    acc.x = d2 * acc.x + bv.x;
    acc.y = d2 * acc.y + bv.y;
    int j = beg;
    for (; j + 4 <= end; j += 4) {
        int2 e0 = eperm[j], e1 = eperm[j + 1], e2 = eperm[j + 2], e3 = eperm[j + 3];
        float2 v0 = hp[(size_t)e0.x * 64 + lane];
        float2 v1 = hp[(size_t)e1.x * 64 + lane];
        float2 v2 = hp[(size_t)e2.x * 64 + lane];
        float2 v3 = hp[(size_t)e3.x * 64 + lane];
        float w0 = __int_as_float(e0.y), w1 = __int_as_float(e1.y);
        float w2 = __int_as_float(e2.y), w3 = __int_as_float(e3.y);
        acc.x += w0 * v0.x + w1 * v1.x + w2 * v2.x + w3 * v3.x;
        acc.y += w0 * v0.y + w1 * v1.y + w2 * v2.y + w3 * v3.y;
    }
    for (; j < end; ++j) {
        int2 e = eperm[j];
        float w = __int_as_float(e.y);
        float2 v = hp[(size_t)e.x * 64 + lane];
        acc.x += w * v.x;
        acc.y += w * v.y;
    }
    ((float2*)out)[(size_t)node * 64 + lane] = acc;
}

__global__ __launch_bounds__(256) void k_gather64(const int* __restrict__ rp,
                                                  const int2* __restrict__ eperm,
                                                  const float* __restrict__ dinv,
                                                  const float* __restrict__ h,
                                                  const float* __restrict__ bias,
                                                  float* __restrict__ out, int n) {
    int node = blockIdx.x * 4 + (threadIdx.x >> 6);
    if (node >= n) return;
    int lane = threadIdx.x & 63;
    int beg = rp[node], end = rp[node + 1];
    float dv = dinv[node];
    float d2 = dv * dv;
    float acc = d2 * h[(size_t)node * 64 + lane] + bias[lane];
    int j = beg;
    for (; j + 4 <= end; j += 4) {
        int2 e0 = eperm[j], e1 = eperm[j + 1], e2 = eperm[j + 2], e3 = eperm[j + 3];
        float v0 = h[(size_t)e0.x * 64 + lane];
        float v1 = h[(size_t)e1.x * 64 + lane];
        float v2 = h[(size_t)e2.x * 64 + lane];
        float v3 = h[(size_t)e3.x * 64 + lane];
        acc += __int_as_float(e0.y) * v0 + __int_as_float(e1.y) * v1 +
               __int_as_float(e2.y) * v2 + __int_as_float(e3.y) * v3;
    }
    for (; j < end; ++j) {
        int2 e = eperm[j];
        acc += __int_as_float(e.y) * h[(size_t)e.x * 64 + lane];
    }
    out[(size_t)node * 64 + lane] = acc;
}

// ---------------- launch ----------------

extern "C" void kernel_launch(void* const* d_in, const int* in_sizes, int n_in,
                              void* d_out, int out_size, void* d_ws, size_t ws_size,
                              hipStream_t stream) {
    const float* x  = (const float*)d_in[0];
    const int*   ei = (const int*)d_in[1];
    const float* W1 = (const float*)d_in[2];
    const float* b1 = (const float*)d_in[3];
    const float* W2 = (const float*)d_in[4];
    const float* b2 = (const float*)d_in[5];
    float* out = (float*)d_out;

    const int N = in_sizes[0] / 128;
    const int E = in_sizes[1] / 2;
    const int* src = ei;
    const int* dst = ei + E;

    char* ws = (char*)d_ws;
    size_t off = 0;
    auto carve = [&](size_t bytes) -> void* {
        void* p = ws + off;
        off = (off + bytes + 255) & ~(size_t)255;
        return p;
    };
    float* dinv = (float*)carve((size_t)N * 4);
    int*   cnt  = (int*)carve((size_t)N * 4);        // histogram; reused as cursor after scan
    int*   rp   = (int*)carve((size_t)(N + 1) * 4);  // partial scan, then row_ptr in place
    int*   bsum = (int*)carve(128 * 4);
    int2*  eperm = (int2*)carve((size_t)E * 8);
    float* h    = (float*)carve((size_t)N * 128 * 4);  // x@W1; reused for h2
    float* hagg = (float*)carve((size_t)N * 128 * 4);
    int* cursor = cnt;  // cnt dead after k_scan1
    float* h2 = h;      // h dead after k_gather128

    const int gN  = (N + THREADS - 1) / THREADS;
    const int gN1 = (N + 1 + THREADS - 1) / THREADS;
    const int gE  = (E + THREADS - 1) / THREADS;
    const int gW  = (N + 3) / 4;       // 4 waves/block gather
    const int gMm = (N + 63) / 64;
    const int nblk = (N + 1023) / 1024;  // <= 128 required

    // CSR build
    k_zero_i<<<gN, THREADS, 0, stream>>>(cnt, N);
    k_hist<<<gE, THREADS, 0, stream>>>(dst, cnt, E);
    k_dinv<<<gN, THREADS, 0, stream>>>(cnt, dinv, N);
    k_scan1<<<nblk, 256, 0, stream>>>(cnt, rp, bsum, N);
    k_scan2<<<1, 128, 0, stream>>>(bsum, nblk);
    k_addoff<<<gN1, THREADS, 0, stream>>>(rp, bsum, cursor, N, E);
    k_permute<<<gE, THREADS, 0, stream>>>(src, dst, dinv, cursor, eperm, E);

    // layer 1
    k_gemm<false><<<dim3(gMm, 2), THREADS, 0, stream>>>(x, W1, h, N, 128);
    k_gather128<<<gW, THREADS, 0, stream>>>(rp, eperm, dinv, h, b1, hagg, N);

    // layer 2
    k_gemm<true><<<dim3(gMm, 1), THREADS, 0, stream>>>(hagg, W2, h2, N, 64);
    k_gather64<<<gW, THREADS, 0, stream>>>(rp, eperm, dinv, h2, b2, out, N);
}

// Round 3
// 438.955 us; speedup vs baseline: 4.4283x; 1.1729x over previous
//
#include <hip/hip_runtime.h>
#include <hip/hip_bf16.h>

#define THREADS 256

// ---------------- helpers ----------------

__device__ inline unsigned short f2bf(float f) {  // round-to-nearest-even
    unsigned int u = __float_as_uint(f);
    unsigned int r = (u + 0x7fffu + ((u >> 16) & 1u)) >> 16;
    return (unsigned short)r;
}

__device__ inline float2 bf2_to_f2(unsigned int u) {  // low bf16 -> x, high bf16 -> y
    float2 r;
    r.x = __uint_as_float(u << 16);
    r.y = __uint_as_float(u & 0xffff0000u);
    return r;
}

// ---------------- CSR build: histogram, dinv, scan, permute ----------------

__global__ void k_zero_i(int* p, int n) {
    int i = blockIdx.x * THREADS + threadIdx.x;
    if (i < n) p[i] = 0;
}

__global__ void k_hist(const int* __restrict__ dst, int* __restrict__ cnt, int E) {
    int e = blockIdx.x * THREADS + threadIdx.x;
    if (e < E) atomicAdd(&cnt[dst[e]], 1);
}

__global__ void k_dinv(const int* __restrict__ cnt, float* __restrict__ dinv, int n) {
    int i = blockIdx.x * THREADS + threadIdx.x;
    if (i < n) dinv[i] = rsqrtf((float)cnt[i] + 1.0f);  // +1 = self-loop
}

__global__ __launch_bounds__(256) void k_scan1(const int* __restrict__ cnt, int* __restrict__ part,
                                               int* __restrict__ bsum, int n) {
    __shared__ int s[256];
    int t = threadIdx.x;
    int base = blockIdx.x * 1024 + t * 4;
    int4 v = make_int4(0, 0, 0, 0);
    if (base + 3 < n) v = *(const int4*)(cnt + base);
    else {
        if (base < n) v.x = cnt[base];
        if (base + 1 < n) v.y = cnt[base + 1];
        if (base + 2 < n) v.z = cnt[base + 2];
        if (base + 3 < n) v.w = cnt[base + 3];
    }
    int mysum = v.x + v.y + v.z + v.w;
    s[t] = mysum;
    __syncthreads();
    for (int off = 1; off < 256; off <<= 1) {
        int add = (t >= off) ? s[t - off] : 0;
        __syncthreads();
        s[t] += add;
        __syncthreads();
    }
    int excl = s[t] - mysum;
    if (base < n) part[base] = excl;
    if (base + 1 < n) part[base + 1] = excl + v.x;
    if (base + 2 < n) part[base + 2] = excl + v.x + v.y;
    if (base + 3 < n) part[base + 3] = excl + v.x + v.y + v.z;
    if (t == 255) bsum[blockIdx.x] = s[255];
}

__global__ void k_scan2(int* bsum, int nblk) {
    __shared__ int s[128];
    int t = threadIdx.x;
    int v = (t < nblk) ? bsum[t] : 0;
    s[t] = v;
    __syncthreads();
    for (int off = 1; off < 128; off <<= 1) {
        int add = (t >= off) ? s[t - off] : 0;
        __syncthreads();
        s[t] += add;
        __syncthreads();
    }
    if (t < nblk) bsum[t] = s[t] - v;  // exclusive
}

__global__ void k_addoff(int* __restrict__ rp, const int* __restrict__ bsum,
                         int* __restrict__ cursor, int n, int E) {
    int i = blockIdx.x * THREADS + threadIdx.x;
    if (i < n) {
        int v = rp[i] + bsum[i >> 10];
        rp[i] = v;
        cursor[i] = v;
    } else if (i == n) {
        rp[n] = E;
    }
}

__global__ void k_permute(const int* __restrict__ src, const int* __restrict__ dst,
                          const float* __restrict__ dinv, int* __restrict__ cursor,
                          int2* __restrict__ eperm, int E) {
    int e = blockIdx.x * THREADS + threadIdx.x;
    if (e >= E) return;
    int s = src[e], d = dst[e];
    int pos = atomicAdd(&cursor[d], 1);
    float w = dinv[s] * dinv[d];
    eperm[pos] = make_int2(s, __float_as_int(w));
}

// ---------------- GEMM: C[M x N](bf16) = A[M x 128](f32) @ W[128 x N](f32) ----------------

template <bool RELU_A>
__global__ __launch_bounds__(256) void k_gemm(const float* __restrict__ A,
                                              const float* __restrict__ W,
                                              unsigned short* __restrict__ C, int M, int N) {
    __shared__ float As[32][68];
    __shared__ float Ws[32][68];
    const int t = threadIdx.x;
    const int m0 = blockIdx.x * 64;
    const int bn0 = blockIdx.y * 64;
    const int tm = t & 15;
    const int tn = t >> 4;
    float acc[4][4] = {};

    for (int kk = 0; kk < 128; kk += 32) {
        {
            int r = t >> 3;
            int c = (t & 7) * 4;
#pragma unroll
            for (int i2 = 0; i2 < 2; ++i2) {
                int row = m0 + r + 32 * i2;
                float4 v = make_float4(0.f, 0.f, 0.f, 0.f);
                if (row < M) v = *(const float4*)(A + (size_t)row * 128 + kk + c);
                if (RELU_A) {
                    v.x = fmaxf(v.x, 0.f); v.y = fmaxf(v.y, 0.f);
                    v.z = fmaxf(v.z, 0.f); v.w = fmaxf(v.w, 0.f);
                }
                As[c + 0][r + 32 * i2] = v.x;
                As[c + 1][r + 32 * i2] = v.y;
                As[c + 2][r + 32 * i2] = v.z;
                As[c + 3][r + 32 * i2] = v.w;
            }
        }
        {
            int r = t >> 4;
            int c = (t & 15) * 4;
#pragma unroll
            for (int i2 = 0; i2 < 2; ++i2) {
                int row = kk + r + 16 * i2;
                *(float4*)&Ws[r + 16 * i2][c] = *(const float4*)(W + (size_t)row * N + bn0 + c);
            }
        }
        __syncthreads();
#pragma unroll
        for (int k = 0; k < 32; ++k) {
            float4 a4 = *(const float4*)&As[k][4 * tm];
            float4 w4 = *(const float4*)&Ws[k][4 * tn];
            float av[4] = {a4.x, a4.y, a4.z, a4.w};
            float wv[4] = {w4.x, w4.y, w4.z, w4.w};
#pragma unroll
            for (int i = 0; i < 4; ++i)
#pragma unroll
                for (int j = 0; j < 4; ++j) acc[i][j] += av[i] * wv[j];
        }
        __syncthreads();
    }
#pragma unroll
    for (int i = 0; i < 4; ++i) {
        int row = m0 + 4 * tm + i;
        if (row < M) {
            ushort4 v;
            v.x = f2bf(acc[i][0]); v.y = f2bf(acc[i][1]);
            v.z = f2bf(acc[i][2]); v.w = f2bf(acc[i][3]);
            *(ushort4*)(C + (size_t)row * N + bn0 + 4 * tn) = v;
        }
    }
}

// ---------------- CSR gather (bf16 features, fp32 accumulate) ----------------
// 128-wide: one wave per node, lane covers 2 feats (4 B). Output fp32.

__global__ __launch_bounds__(256) void k_gather128(const int* __restrict__ rp,
                                                   const int2* __restrict__ eperm,
                                                   const float* __restrict__ dinv,
                                                   const unsigned int* __restrict__ h,  // bf16x2
                                                   const float* __restrict__ bias,
                                                   float* __restrict__ out, int n) {
    int node = blockIdx.x * 4 + (threadIdx.x >> 6);
    if (node >= n) return;
    int lane = threadIdx.x & 63;
    int beg = rp[node], end = rp[node + 1];
    float dv = dinv[node];
    float d2 = dv * dv;
    float2 self = bf2_to_f2(h[(size_t)node * 64 + lane]);
    float2 bv = ((const float2*)bias)[lane];
    float2 acc = make_float2(d2 * self.x + bv.x, d2 * self.y + bv.y);
    int j = beg;
    for (; j + 4 <= end; j += 4) {
        int2 e0 = eperm[j], e1 = eperm[j + 1], e2 = eperm[j + 2], e3 = eperm[j + 3];
        float2 v0 = bf2_to_f2(h[(size_t)e0.x * 64 + lane]);
        float2 v1 = bf2_to_f2(h[(size_t)e1.x * 64 + lane]);
        float2 v2 = bf2_to_f2(h[(size_t)e2.x * 64 + lane]);
        float2 v3 = bf2_to_f2(h[(size_t)e3.x * 64 + lane]);
        float w0 = __int_as_float(e0.y), w1 = __int_as_float(e1.y);
        float w2 = __int_as_float(e2.y), w3 = __int_as_float(e3.y);
        acc.x += w0 * v0.x + w1 * v1.x + w2 * v2.x + w3 * v3.x;
        acc.y += w0 * v0.y + w1 * v1.y + w2 * v2.y + w3 * v3.y;
    }
    for (; j < end; ++j) {
        int2 e = eperm[j];
        float w = __int_as_float(e.y);
        float2 v = bf2_to_f2(h[(size_t)e.x * 64 + lane]);
        acc.x += w * v.x;
        acc.y += w * v.y;
    }
    ((float2*)out)[(size_t)node * 64 + lane] = acc;
}

// 64-wide: one wave per node; half-waves split the edge list (even/odd), each
// lane covers 2 feats (4 B); combine halves with shfl_xor(32). Output fp32.

__global__ __launch_bounds__(256) void k_gather64(const int* __restrict__ rp,
                                                  const int2* __restrict__ eperm,
                                                  const float* __restrict__ dinv,
                                                  const unsigned int* __restrict__ h,  // bf16x2
                                                  const float* __restrict__ bias,
                                                  float* __restrict__ out, int n) {
    int node = blockIdx.x * 4 + (threadIdx.x >> 6);
    if (node >= n) return;
    int t = threadIdx.x;
    int l32 = t & 31;
    int half = (t >> 5) & 1;
    int beg = rp[node], end = rp[node + 1];
    float2 acc = make_float2(0.f, 0.f);
    if (half == 0) {
        float dv = dinv[node];
        float d2 = dv * dv;
        float2 self = bf2_to_f2(h[(size_t)node * 32 + l32]);
        float2 bv = ((const float2*)bias)[l32];
        acc.x = d2 * self.x + bv.x;
        acc.y = d2 * self.y + bv.y;
    }
    int j = beg + half;
    for (; j + 6 < end; j += 8) {
        int2 e0 = eperm[j], e1 = eperm[j + 2], e2 = eperm[j + 4], e3 = eperm[j + 6];
        float2 v0 = bf2_to_f2(h[(size_t)e0.x * 32 + l32]);
        float2 v1 = bf2_to_f2(h[(size_t)e1.x * 32 + l32]);
        float2 v2 = bf2_to_f2(h[(size_t)e2.x * 32 + l32]);
        float2 v3 = bf2_to_f2(h[(size_t)e3.x * 32 + l32]);
        float w0 = __int_as_float(e0.y), w1 = __int_as_float(e1.y);
        float w2 = __int_as_float(e2.y), w3 = __int_as_float(e3.y);
        acc.x += w0 * v0.x + w1 * v1.x + w2 * v2.x + w3 * v3.x;
        acc.y += w0 * v0.y + w1 * v1.y + w2 * v2.y + w3 * v3.y;
    }
    for (; j < end; j += 2) {
        int2 e = eperm[j];
        float w = __int_as_float(e.y);
        float2 v = bf2_to_f2(h[(size_t)e.x * 32 + l32]);
        acc.x += w * v.x;
        acc.y += w * v.y;
    }
    acc.x += __shfl_xor(acc.x, 32);
    acc.y += __shfl_xor(acc.y, 32);
    if (half == 0) ((float2*)out)[(size_t)node * 32 + l32] = acc;
}

// ---------------- launch ----------------

extern "C" void kernel_launch(void* const* d_in, const int* in_sizes, int n_in,
                              void* d_out, int out_size, void* d_ws, size_t ws_size,
                              hipStream_t stream) {
    const float* x  = (const float*)d_in[0];
    const int*   ei = (const int*)d_in[1];
    const float* W1 = (const float*)d_in[2];
    const float* b1 = (const float*)d_in[3];
    const float* W2 = (const float*)d_in[4];
    const float* b2 = (const float*)d_in[5];
    float* out = (float*)d_out;

    const int N = in_sizes[0] / 128;
    const int E = in_sizes[1] / 2;
    const int* src = ei;
    const int* dst = ei + E;

    char* ws = (char*)d_ws;
    size_t off = 0;
    auto carve = [&](size_t bytes) -> void* {
        void* p = ws + off;
        off = (off + bytes + 255) & ~(size_t)255;
        return p;
    };
    float* dinv = (float*)carve((size_t)N * 4);
    int*   cnt  = (int*)carve((size_t)N * 4);
    int*   rp   = (int*)carve((size_t)(N + 1) * 4);
    int*   bsum = (int*)carve(128 * 4);
    int2*  eperm = (int2*)carve((size_t)E * 8);
    unsigned short* h = (unsigned short*)carve((size_t)N * 128 * 2);  // bf16 x@W1; reused for h2
    float* hagg = (float*)carve((size_t)N * 128 * 4);                 // fp32 aggregated layer 1
    int* cursor = cnt;
    unsigned short* h2 = h;

    const int gN  = (N + THREADS - 1) / THREADS;
    const int gN1 = (N + 1 + THREADS - 1) / THREADS;
    const int gE  = (E + THREADS - 1) / THREADS;
    const int gW  = (N + 3) / 4;
    const int gMm = (N + 63) / 64;
    const int nblk = (N + 1023) / 1024;

    // CSR build
    k_zero_i<<<gN, THREADS, 0, stream>>>(cnt, N);
    k_hist<<<gE, THREADS, 0, stream>>>(dst, cnt, E);
    k_dinv<<<gN, THREADS, 0, stream>>>(cnt, dinv, N);
    k_scan1<<<nblk, 256, 0, stream>>>(cnt, rp, bsum, N);
    k_scan2<<<1, 128, 0, stream>>>(bsum, nblk);
    k_addoff<<<gN1, THREADS, 0, stream>>>(rp, bsum, cursor, N, E);
    k_permute<<<gE, THREADS, 0, stream>>>(src, dst, dinv, cursor, eperm, E);

    // layer 1
    k_gemm<false><<<dim3(gMm, 2), THREADS, 0, stream>>>(x, W1, h, N, 128);
    k_gather128<<<gW, THREADS, 0, stream>>>(rp, eperm, dinv, (const unsigned int*)h, b1, hagg, N);

    // layer 2
    k_gemm<true><<<dim3(gMm, 1), THREADS, 0, stream>>>(hagg, W2, h2, N, 64);
    k_gather64<<<gW, THREADS, 0, stream>>>(rp, eperm, dinv, (const unsigned int*)h2, b2, out, N);
}